// Round 1
// baseline (308.552 us; speedup 1.0000x reference)
//
#include <hip/hip_runtime.h>
#include <hip/hip_bf16.h>
#include <math.h>

#define CH 64
#define NXCD 8

typedef short short8 __attribute__((ext_vector_type(8)));
typedef float floatx4 __attribute__((ext_vector_type(4)));

__device__ __forceinline__ float bf2f(unsigned short u) {
    return __uint_as_float(((unsigned int)u) << 16);
}
__device__ __forceinline__ unsigned short f2bf(float f) {
    unsigned int x = __float_as_uint(f);
    unsigned int r = (x + 0x7fff + ((x >> 16) & 1)) >> 16;   // RNE
    return (unsigned short)r;
}

// ---------------------------------------------------------------------------
// Single-pass degree histogram (validity check matches k_permute exactly so
// deg == committed entries). Block 0 runs the bf16-vs-fp32 dtype detector.
// ---------------------------------------------------------------------------
__global__ __launch_bounds__(256) void k_hist(
    const unsigned short* __restrict__ x,
    const int* __restrict__ srcs, const int* __restrict__ dsts,
    int* __restrict__ deg, int* __restrict__ flag,
    int n_edges, int n_nodes)
{
    if (blockIdx.x == 0 && threadIdx.x < 64) {
        unsigned short u = x[2 * threadIdx.x];
        int ex = (u >> 7) & 0xFF;
        bool insane = (ex < 0x60) || (ex > 0x9F);
        unsigned long long m = __ballot(insane);
        if (threadIdx.x == 0) flag[0] = (__popcll(m) > 16) ? 0 : 1;
    }
    int e = blockIdx.x * 256 + threadIdx.x;
    if (e >= n_edges) return;
    int d = dsts[e], s = srcs[e];
    if ((unsigned)d < (unsigned)n_nodes && (unsigned)s < (unsigned)n_nodes)
        atomicAdd(&deg[d], 1);
}

// ---------------------------------------------------------------------------
// Exclusive scan: per-1024 block partials -> block-sum scan -> add-back.
// rowptr has n+1 entries; k_scan2 writes rowptr[n] = total.
// ---------------------------------------------------------------------------
__global__ __launch_bounds__(256) void k_scan1(
    const int* __restrict__ deg, int* __restrict__ rowptr,
    int* __restrict__ bsum, int n)
{
    __shared__ int ts[256];
    int t = threadIdx.x;
    int base = blockIdx.x * 1024 + t * 4;
    int v[4], local = 0;
    #pragma unroll
    for (int k = 0; k < 4; k++) { v[k] = (base + k < n) ? deg[base + k] : 0; local += v[k]; }
    ts[t] = local; __syncthreads();
    for (int off = 1; off < 256; off <<= 1) {
        int val = (t >= off) ? ts[t - off] : 0;
        __syncthreads();
        ts[t] += val;
        __syncthreads();
    }
    int run = ts[t] - local;
    #pragma unroll
    for (int k = 0; k < 4; k++) { if (base + k < n) rowptr[base + k] = run; run += v[k]; }
    if (t == 255) bsum[blockIdx.x] = ts[255];
}

__global__ __launch_bounds__(256) void k_scan2(
    int* __restrict__ bsum, int* __restrict__ rowptr, int nb, int n)
{
    __shared__ int ts[256];
    int t = threadIdx.x;
    int base = t * 4;
    int v[4], local = 0;
    #pragma unroll
    for (int k = 0; k < 4; k++) { v[k] = (base + k < nb) ? bsum[base + k] : 0; local += v[k]; }
    ts[t] = local; __syncthreads();
    for (int off = 1; off < 256; off <<= 1) {
        int val = (t >= off) ? ts[t - off] : 0;
        __syncthreads();
        ts[t] += val;
        __syncthreads();
    }
    int run = ts[t] - local;
    #pragma unroll
    for (int k = 0; k < 4; k++) { if (base + k < nb) bsum[base + k] = run; run += v[k]; }
    if (t == 255) rowptr[n] = ts[255];       // grand total
}

__global__ __launch_bounds__(256) void k_scan3(
    int* __restrict__ rowptr, int* __restrict__ cursor,
    const int* __restrict__ bsum, int n)
{
    int add = bsum[blockIdx.x];
    int base = blockIdx.x * 1024 + threadIdx.x * 4;
    #pragma unroll
    for (int k = 0; k < 4; k++) {
        int i = base + k;
        if (i < n) { int r = rowptr[i] + add; rowptr[i] = r; cursor[i] = r; }
    }
}

// ---------------------------------------------------------------------------
// XCD-owned permute: blocks with (blockIdx&7)==g scan all edges, commit only
// dsts in range g -> every nbr/cursor line is written by exactly one XCD
// (kills cross-XCD partial-line writeback ping-pong; verified round 7).
// blockIdx&7 ~ XCD id is a perf heuristic only; atomics are device-scope.
// ---------------------------------------------------------------------------
__global__ __launch_bounds__(256) void k_permute(
    const int* __restrict__ srcs, const int* __restrict__ dsts,
    int* __restrict__ cursor, int* __restrict__ nbr, int n_edges, int n_nodes)
{
    const int grp = blockIdx.x & (NXCD - 1);
    const int gidx = blockIdx.x >> 3;
    const int gstride = (gridDim.x >> 3) * 256;
    const int range = (n_nodes + NXCD - 1) / NXCD;
    const int lo = grp * range;
    const int hi = min(n_nodes, lo + range);
    for (int e = gidx * 256 + threadIdx.x; e < n_edges; e += gstride) {
        int d = dsts[e];
        if (d >= lo && d < hi) {
            int s = srcs[e];
            if ((unsigned)s < (unsigned)n_nodes) {
                int pos = atomicAdd(&cursor[d], 1);
                nbr[pos] = s;
            }
        }
    }
}

// ---------------------------------------------------------------------------
// Fused gather-mean + SAGE matmul. One block = 4 waves x 4 nodes = one
// 16-node MFMA tile.
//  Phase 1 (verified gather v2, unchanged inner loop): lane = t(node) x
//   s(parity) x c(16B chunk); 8 independent 16B row loads in flight; slot
//   reduce via shfl_xor(8); mean row -> LDS tile [16][72] bf16 (row pad +8
//   shorts -> 2-way bank alias only, free).
//  Phase 2: wave w computes out-ch slice [16w,16w+16): 4x mfma_16x16x32_bf16
//   D = mean@Wl^T + x_self@Wr^T + bias; A-frags from LDS (lane&15 = node row,
//   verified k_mm mapping), ReLU -> h, or fused head -> sigmoid out.
// Eliminates the mean global round-trip and the separate k_mm dispatches;
// the matmul rides under the gather's L2-miss latency wall.
// XMODE 0: xin dtype per flag. XMODE 1: xin is bf16.
// ---------------------------------------------------------------------------
template <int XMODE, bool HEAD>
__global__ __launch_bounds__(256) void k_fused(
    const int* __restrict__ flag, const void* __restrict__ xin,
    const int* __restrict__ nbr, const int* __restrict__ rowptr,
    const void* __restrict__ w_l, const void* __restrict__ bias,
    const void* __restrict__ w_r,
    const void* __restrict__ w_out, const void* __restrict__ b_out,
    void* __restrict__ outp, int n_nodes)
{
    const int isbf = flag[0];
    const bool xbf = (XMODE == 1) ? true : (isbf != 0);
    const int lane = threadIdx.x & 63;
    const int wid  = threadIdx.x >> 6;
    const int base = blockIdx.x * 16;

    __shared__ __align__(16) unsigned short smean[16][72];  // +8 pad: bank-safe
    __shared__ float psum[4][16];

    const unsigned short* xu = (const unsigned short*)xin;
    const float*          xf = (const float*)xin;

    // ---------------- phase 1: gather-mean into LDS ----------------
    {
        const int t = lane >> 4;          // node slot
        const int s = (lane >> 3) & 1;    // neighbor parity
        const int c = lane & 7;           // 16B channel chunk
        int node = base + wid * 4 + t;
        bool nv = node < n_nodes;
        int r0 = 0, d = 0;
        if (nv) { r0 = rowptr[node]; d = rowptr[node + 1] - r0; }

        // wave-uniform loop bound (within a node all 16 lanes share d)
        int dmax = d;
        dmax = max(dmax, __shfl_xor(dmax, 16));
        dmax = max(dmax, __shfl_xor(dmax, 32));

        if (xbf) {
            floatx4 a0 = {0, 0, 0, 0}, a1 = {0, 0, 0, 0};
            for (int jb = 0; jb < dmax; jb += 16) {
                #pragma unroll
                for (int k = 0; k < 8; k++) {
                    int j = jb + k * 2 + s;
                    if (j < d) {
                        int src = nbr[r0 + j];
                        short8 v = *(const short8*)(xu + (size_t)src * CH + c * 8);
                        #pragma unroll
                        for (int i = 0; i < 4; i++) a0[i] += bf2f((unsigned short)v[i]);
                        #pragma unroll
                        for (int i = 0; i < 4; i++) a1[i] += bf2f((unsigned short)v[4 + i]);
                    }
                }
            }
            #pragma unroll
            for (int i = 0; i < 4; i++) {
                a0[i] += __shfl_xor(a0[i], 8);
                a1[i] += __shfl_xor(a1[i], 8);
            }
            if ((lane & 8) == 0) {
                float inv = 1.0f / (float)max(d, 1);
                short8 mv;
                #pragma unroll
                for (int i = 0; i < 4; i++) {
                    mv[i]     = (short)f2bf(a0[i] * inv);
                    mv[4 + i] = (short)f2bf(a1[i] * inv);
                }
                *(short8*)(&smean[wid * 4 + t][c * 8]) = mv;
            }
        } else {
            // fp32 input (cold correctness path): 16 lanes/node, lane covers 4 ch
            int j16 = lane & 15;
            floatx4 acc = {0, 0, 0, 0};
            for (int j = 0; j < d; j++) {
                int src = nbr[r0 + j];
                acc += *(const floatx4*)(xf + (size_t)src * CH + j16 * 4);
            }
            float inv = 1.0f / (float)max(d, 1);
            #pragma unroll
            for (int i = 0; i < 4; i++)
                smean[wid * 4 + t][j16 * 4 + i] = f2bf(acc[i] * inv);
        }
    }
    __syncthreads();

    // ---------------- phase 2: MFMA tile, one out-ch slice per wave --------
    const int n_ = lane & 15;
    const int q_ = lane >> 4;
    const int row = wid * 16 + n_;       // out-channel = row of W

    short8 wlf[2], wrf[2];
    float bv, wov = 0.0f;
    if (isbf) {
        const unsigned short* wl = (const unsigned short*)w_l;
        const unsigned short* wr = (const unsigned short*)w_r;
        #pragma unroll
        for (int kc = 0; kc < 2; kc++) {
            int k0 = kc * 32 + q_ * 8;
            wlf[kc] = *(const short8*)(wl + row * CH + k0);
            wrf[kc] = *(const short8*)(wr + row * CH + k0);
        }
        bv = bf2f(((const unsigned short*)bias)[row]);
        if (HEAD) wov = bf2f(((const unsigned short*)w_out)[row]);
    } else {
        const float* wl = (const float*)w_l;
        const float* wr = (const float*)w_r;
        #pragma unroll
        for (int kc = 0; kc < 2; kc++) {
            int k0 = kc * 32 + q_ * 8;
            #pragma unroll
            for (int j = 0; j < 8; j++) {
                wlf[kc][j] = (short)f2bf(wl[row * CH + k0 + j]);
                wrf[kc][j] = (short)f2bf(wr[row * CH + k0 + j]);
            }
        }
        bv = ((const float*)bias)[row];
        if (HEAD) wov = ((const float*)w_out)[row];
    }

    // A-frags: mean from LDS, x_self from global (verified k_mm mapping:
    // lane&15 = node row, (lane>>4)*8 = k chunk)
    short8 am0 = *(const short8*)(&smean[n_][q_ * 8]);
    short8 am1 = *(const short8*)(&smean[n_][32 + q_ * 8]);
    int node_m = base + n_;
    int node_c = (node_m < n_nodes) ? node_m : 0;
    short8 ax0, ax1;
    if (xbf) {
        ax0 = *(const short8*)(xu + (size_t)node_c * CH + q_ * 8);
        ax1 = *(const short8*)(xu + (size_t)node_c * CH + 32 + q_ * 8);
    } else {
        const float* p = xf + (size_t)node_c * CH;
        #pragma unroll
        for (int j = 0; j < 8; j++) {
            ax0[j] = (short)f2bf(p[q_ * 8 + j]);
            ax1[j] = (short)f2bf(p[32 + q_ * 8 + j]);
        }
    }

    floatx4 acc = {bv, bv, bv, bv};
    acc = __builtin_amdgcn_mfma_f32_16x16x32_bf16(am0, wlf[0], acc, 0, 0, 0);
    acc = __builtin_amdgcn_mfma_f32_16x16x32_bf16(am1, wlf[1], acc, 0, 0, 0);
    acc = __builtin_amdgcn_mfma_f32_16x16x32_bf16(ax0, wrf[0], acc, 0, 0, 0);
    acc = __builtin_amdgcn_mfma_f32_16x16x32_bf16(ax1, wrf[1], acc, 0, 0, 0);

    if (!HEAD) {
        // C/D layout: col = lane&15 (out-ch), row = q_*4+reg (node)
        unsigned short* ho = (unsigned short*)outp;
        int cc = wid * 16 + n_;
        #pragma unroll
        for (int reg = 0; reg < 4; reg++) {
            int node_r = base + q_ * 4 + reg;
            if (node_r < n_nodes)
                ho[(size_t)node_r * CH + cc] = f2bf(fmaxf(acc[reg], 0.0f));
        }
    } else {
        float p[4];
        #pragma unroll
        for (int reg = 0; reg < 4; reg++)
            p[reg] = fmaxf(acc[reg], 0.0f) * wov;
        #pragma unroll
        for (int off = 1; off < 16; off <<= 1) {
            #pragma unroll
            for (int reg = 0; reg < 4; reg++)
                p[reg] += __shfl_xor(p[reg], off);
        }
        if (n_ == 0) {
            #pragma unroll
            for (int reg = 0; reg < 4; reg++)
                psum[wid][q_ * 4 + reg] = p[reg];
        }
        __syncthreads();
        if (threadIdx.x < 16) {
            int node_r = base + threadIdx.x;
            if (node_r < n_nodes) {
                float bo = isbf ? bf2f(((const unsigned short*)b_out)[0])
                                : ((const float*)b_out)[0];
                float v = psum[0][threadIdx.x] + psum[1][threadIdx.x]
                        + psum[2][threadIdx.x] + psum[3][threadIdx.x] + bo;
                float sg = 1.0f / (1.0f + expf(-v));
                if (isbf) ((unsigned short*)outp)[node_r] = f2bf(sg);
                else      ((float*)outp)[node_r] = sg;
            }
        }
    }
}

extern "C" void kernel_launch(void* const* d_in, const int* in_sizes, int n_in,
                              void* d_out, int out_size, void* d_ws, size_t ws_size,
                              hipStream_t stream)
{
    const void* x    = d_in[0];
    const int*  ei   = (const int*)d_in[1];
    const void* w1_l = d_in[2];
    const void* b1   = d_in[3];
    const void* w1_r = d_in[4];
    const void* w2_l = d_in[5];
    const void* b2   = d_in[6];
    const void* w2_r = d_in[7];
    const void* wout = d_in[8];
    const void* bout = d_in[9];

    int n_nodes = out_size;
    int n_edges = in_sizes[1] / 2;
    const int* srcs = ei;
    const int* dsts = ei + n_edges;

    // ws: [flag][deg n][rowptr n+1][cursor n][bsum 1024][nbr E][h n*64]
    char* wsb = (char*)d_ws;
    size_t off = 0;
    auto carve = [&](size_t bytes) { size_t p = off; off = (off + bytes + 255) & ~(size_t)255; return p; };
    size_t flag_off = carve(sizeof(int));
    size_t deg_off  = carve((size_t)n_nodes * sizeof(int));
    size_t row_off  = carve((size_t)(n_nodes + 1) * sizeof(int));
    size_t cur_off  = carve((size_t)n_nodes * sizeof(int));
    size_t bs_off   = carve(1024 * sizeof(int));
    size_t nbr_off  = carve((size_t)n_edges * sizeof(int));
    size_t h_off    = carve((size_t)n_nodes * CH * sizeof(unsigned short));
    int* flag   = (int*)(wsb + flag_off);
    int* deg    = (int*)(wsb + deg_off);
    int* rowptr = (int*)(wsb + row_off);
    int* cursor = (int*)(wsb + cur_off);
    int* bsum   = (int*)(wsb + bs_off);
    int* nbr    = (int*)(wsb + nbr_off);
    unsigned short* h = (unsigned short*)(wsb + h_off);

    int eblocks = (n_edges + 255) / 256;
    int xblocks = 2048;                          // XCD-owned permute
    int nb1     = (n_nodes + 1023) / 1024;
    int fblocks = (n_nodes + 15) / 16;           // fused: 16 nodes = 1 tile/block

    hipMemsetAsync(deg, 0, (size_t)n_nodes * sizeof(int), stream);

    // CSR build (+ dtype detect inside k_hist)
    k_hist<<<eblocks, 256, 0, stream>>>((const unsigned short*)x, srcs, dsts, deg, flag, n_edges, n_nodes);
    k_scan1<<<nb1, 256, 0, stream>>>(deg, rowptr, bsum, n_nodes);
    k_scan2<<<1, 256, 0, stream>>>(bsum, rowptr, nb1, n_nodes);
    k_scan3<<<nb1, 256, 0, stream>>>(rowptr, cursor, bsum, n_nodes);
    k_permute<<<xblocks, 256, 0, stream>>>(srcs, dsts, cursor, nbr, n_edges, n_nodes);

    // layer 1: x -> h (fused gather+mm)
    k_fused<0, false><<<fblocks, 256, 0, stream>>>(flag, x, nbr, rowptr,
                                                   w1_l, b1, w1_r,
                                                   nullptr, nullptr, h, n_nodes);
    // layer 2 + head: h -> out (fused gather+mm+head)
    k_fused<1, true><<<fblocks, 256, 0, stream>>>(flag, h, nbr, rowptr,
                                                  w2_l, b2, w2_r,
                                                  wout, bout, d_out, n_nodes);
}

// Round 2
// 293.300 us; speedup vs baseline: 1.0520x; 1.0520x over previous
//
#include <hip/hip_runtime.h>
#include <hip/hip_bf16.h>
#include <math.h>

#define CH 64
#define NXCD 8

typedef short short8 __attribute__((ext_vector_type(8)));
typedef float floatx4 __attribute__((ext_vector_type(4)));

__device__ __forceinline__ float bf2f(unsigned short u) {
    return __uint_as_float(((unsigned int)u) << 16);
}
__device__ __forceinline__ unsigned short f2bf(float f) {
    unsigned int x = __float_as_uint(f);
    unsigned int r = (x + 0x7fff + ((x >> 16) & 1)) >> 16;   // RNE
    return (unsigned short)r;
}

// ---------------------------------------------------------------------------
// Single-pass degree histogram (validity check matches k_permute exactly so
// deg == committed entries). Block 0 runs the bf16-vs-fp32 dtype detector.
// ---------------------------------------------------------------------------
__global__ __launch_bounds__(256) void k_hist(
    const unsigned short* __restrict__ x,
    const int* __restrict__ srcs, const int* __restrict__ dsts,
    int* __restrict__ deg, int* __restrict__ flag,
    int n_edges, int n_nodes)
{
    if (blockIdx.x == 0 && threadIdx.x < 64) {
        unsigned short u = x[2 * threadIdx.x];
        int ex = (u >> 7) & 0xFF;
        bool insane = (ex < 0x60) || (ex > 0x9F);
        unsigned long long m = __ballot(insane);
        if (threadIdx.x == 0) flag[0] = (__popcll(m) > 16) ? 0 : 1;
    }
    int e = blockIdx.x * 256 + threadIdx.x;
    if (e >= n_edges) return;
    int d = dsts[e], s = srcs[e];
    if ((unsigned)d < (unsigned)n_nodes && (unsigned)s < (unsigned)n_nodes)
        atomicAdd(&deg[d], 1);
}

// ---------------------------------------------------------------------------
// Exclusive scan: per-1024 block partials -> block-sum scan -> add-back.
// rowptr has n+1 entries; k_scan2 writes rowptr[n] = total.
// ---------------------------------------------------------------------------
__global__ __launch_bounds__(256) void k_scan1(
    const int* __restrict__ deg, int* __restrict__ rowptr,
    int* __restrict__ bsum, int n)
{
    __shared__ int ts[256];
    int t = threadIdx.x;
    int base = blockIdx.x * 1024 + t * 4;
    int v[4], local = 0;
    #pragma unroll
    for (int k = 0; k < 4; k++) { v[k] = (base + k < n) ? deg[base + k] : 0; local += v[k]; }
    ts[t] = local; __syncthreads();
    for (int off = 1; off < 256; off <<= 1) {
        int val = (t >= off) ? ts[t - off] : 0;
        __syncthreads();
        ts[t] += val;
        __syncthreads();
    }
    int run = ts[t] - local;
    #pragma unroll
    for (int k = 0; k < 4; k++) { if (base + k < n) rowptr[base + k] = run; run += v[k]; }
    if (t == 255) bsum[blockIdx.x] = ts[255];
}

__global__ __launch_bounds__(256) void k_scan2(
    int* __restrict__ bsum, int* __restrict__ rowptr, int nb, int n)
{
    __shared__ int ts[256];
    int t = threadIdx.x;
    int base = t * 4;
    int v[4], local = 0;
    #pragma unroll
    for (int k = 0; k < 4; k++) { v[k] = (base + k < nb) ? bsum[base + k] : 0; local += v[k]; }
    ts[t] = local; __syncthreads();
    for (int off = 1; off < 256; off <<= 1) {
        int val = (t >= off) ? ts[t - off] : 0;
        __syncthreads();
        ts[t] += val;
        __syncthreads();
    }
    int run = ts[t] - local;
    #pragma unroll
    for (int k = 0; k < 4; k++) { if (base + k < nb) bsum[base + k] = run; run += v[k]; }
    if (t == 255) rowptr[n] = ts[255];       // grand total
}

__global__ __launch_bounds__(256) void k_scan3(
    int* __restrict__ rowptr, int* __restrict__ cursor,
    const int* __restrict__ bsum, int n)
{
    int add = bsum[blockIdx.x];
    int base = blockIdx.x * 1024 + threadIdx.x * 4;
    #pragma unroll
    for (int k = 0; k < 4; k++) {
        int i = base + k;
        if (i < n) { int r = rowptr[i] + add; rowptr[i] = r; cursor[i] = r; }
    }
}

// ---------------------------------------------------------------------------
// XCD-owned permute: blocks with (blockIdx&7)==g scan all edges, commit only
// dsts in range g -> every nbr/cursor line is written by exactly one XCD
// (kills cross-XCD partial-line writeback ping-pong; verified round 7).
// blockIdx&7 ~ XCD id is a perf heuristic only; atomics are device-scope.
// ---------------------------------------------------------------------------
__global__ __launch_bounds__(256) void k_permute(
    const int* __restrict__ srcs, const int* __restrict__ dsts,
    int* __restrict__ cursor, int* __restrict__ nbr, int n_edges, int n_nodes)
{
    const int grp = blockIdx.x & (NXCD - 1);
    const int gidx = blockIdx.x >> 3;
    const int gstride = (gridDim.x >> 3) * 256;
    const int range = (n_nodes + NXCD - 1) / NXCD;
    const int lo = grp * range;
    const int hi = min(n_nodes, lo + range);
    for (int e = gidx * 256 + threadIdx.x; e < n_edges; e += gstride) {
        int d = dsts[e];
        if (d >= lo && d < hi) {
            int s = srcs[e];
            if ((unsigned)s < (unsigned)n_nodes) {
                int pos = atomicAdd(&cursor[d], 1);
                nbr[pos] = s;
            }
        }
    }
}

// ---------------------------------------------------------------------------
// Wave-fused gather-mean + SAGE matmul. ZERO barriers: each wave owns one
// 16-node tile end-to-end, so finished waves retire and free slots (round-1's
// block-barrier version parked finished waves at s_barrier -> BW 2.6->1.7).
//  Gather: 4 lanes/node (n16=lane>>2, c4=lane&3); each lane owns 16 DISTINCT
//   channels -> no cross-lane reduce. Unroll 4 neighbors x 2x16B loads = 8
//   independent loads in flight/lane. Mean -> per-wave LDS [16][72] bf16
//   (row stride 144B: frag ds_read_b128 aliases 2-way only = free).
//  Ordering: own-wave lgkmcnt(0) only (no s_barrier).
//  MFMA: verified k_mm tile body; och-slice loop kept ROLLED (#pragma
//   unroll 1) so weight frags reload per slice (L1-hot 512B) instead of
//   pinning 64 VGPRs across the gather.
//  C/D layout: col = lane&15 (och), row = (lane>>4)*4 + reg (node).
// XMODE 0: xin dtype per flag. XMODE 1: xin is bf16.
// ---------------------------------------------------------------------------
template <int XMODE, bool HEAD>
__global__ __launch_bounds__(256) void k_fused(
    const int* __restrict__ flag, const void* __restrict__ xin,
    const int* __restrict__ nbr, const int* __restrict__ rowptr,
    const void* __restrict__ w_l, const void* __restrict__ bias,
    const void* __restrict__ w_r,
    const void* __restrict__ w_out, const void* __restrict__ b_out,
    void* __restrict__ outp, int n_nodes)
{
    const int isbf = flag[0];
    const bool xbf = (XMODE == 1) ? true : (isbf != 0);
    const int lane = threadIdx.x & 63;
    const int wid  = threadIdx.x >> 6;

    __shared__ __align__(16) unsigned short sm[4][16][72];   // per-wave tiles

    const int tilebase = (blockIdx.x * 4 + wid) * 16;
    if (tilebase >= n_nodes) return;

    const unsigned short* xu = (const unsigned short*)xin;
    const float*          xf = (const float*)xin;

    // ---------------- phase 1: gather-mean into per-wave LDS ----------------
    {
        const int n16 = lane >> 2;        // node within tile
        const int c4  = lane & 3;         // 32B channel chunk: ch c4*16..+15
        int node = tilebase + n16;
        bool nv = node < n_nodes;
        int r0 = 0, d = 0;
        if (nv) { r0 = rowptr[node]; d = rowptr[node + 1] - r0; }

        // wave-uniform loop bound (d uniform within each 4-lane node group)
        int dmax = d;
        dmax = max(dmax, __shfl_xor(dmax, 4));
        dmax = max(dmax, __shfl_xor(dmax, 8));
        dmax = max(dmax, __shfl_xor(dmax, 16));
        dmax = max(dmax, __shfl_xor(dmax, 32));

        floatx4 a0 = {0,0,0,0}, a1 = {0,0,0,0}, a2 = {0,0,0,0}, a3 = {0,0,0,0};

        if (xbf) {
            for (int jb = 0; jb < dmax; jb += 4) {
                int id0 = (jb + 0 < d) ? nbr[r0 + jb + 0] : -1;
                int id1 = (jb + 1 < d) ? nbr[r0 + jb + 1] : -1;
                int id2 = (jb + 2 < d) ? nbr[r0 + jb + 2] : -1;
                int id3 = (jb + 3 < d) ? nbr[r0 + jb + 3] : -1;
                short8 v00, v01, v10, v11, v20, v21, v30, v31;
                if (id0 >= 0) { const unsigned short* p = xu + (size_t)id0 * CH + c4 * 16;
                                v00 = *(const short8*)p; v01 = *(const short8*)(p + 8); }
                if (id1 >= 0) { const unsigned short* p = xu + (size_t)id1 * CH + c4 * 16;
                                v10 = *(const short8*)p; v11 = *(const short8*)(p + 8); }
                if (id2 >= 0) { const unsigned short* p = xu + (size_t)id2 * CH + c4 * 16;
                                v20 = *(const short8*)p; v21 = *(const short8*)(p + 8); }
                if (id3 >= 0) { const unsigned short* p = xu + (size_t)id3 * CH + c4 * 16;
                                v30 = *(const short8*)p; v31 = *(const short8*)(p + 8); }
                if (id0 >= 0) {
                    #pragma unroll
                    for (int i = 0; i < 4; i++) { a0[i] += bf2f((unsigned short)v00[i]);
                                                  a1[i] += bf2f((unsigned short)v00[4+i]);
                                                  a2[i] += bf2f((unsigned short)v01[i]);
                                                  a3[i] += bf2f((unsigned short)v01[4+i]); }
                }
                if (id1 >= 0) {
                    #pragma unroll
                    for (int i = 0; i < 4; i++) { a0[i] += bf2f((unsigned short)v10[i]);
                                                  a1[i] += bf2f((unsigned short)v10[4+i]);
                                                  a2[i] += bf2f((unsigned short)v11[i]);
                                                  a3[i] += bf2f((unsigned short)v11[4+i]); }
                }
                if (id2 >= 0) {
                    #pragma unroll
                    for (int i = 0; i < 4; i++) { a0[i] += bf2f((unsigned short)v20[i]);
                                                  a1[i] += bf2f((unsigned short)v20[4+i]);
                                                  a2[i] += bf2f((unsigned short)v21[i]);
                                                  a3[i] += bf2f((unsigned short)v21[4+i]); }
                }
                if (id3 >= 0) {
                    #pragma unroll
                    for (int i = 0; i < 4; i++) { a0[i] += bf2f((unsigned short)v30[i]);
                                                  a1[i] += bf2f((unsigned short)v30[4+i]);
                                                  a2[i] += bf2f((unsigned short)v31[i]);
                                                  a3[i] += bf2f((unsigned short)v31[4+i]); }
                }
            }
        } else {
            // fp32 input (cold correctness path)
            for (int j = 0; j < d; j++) {
                int src = nbr[r0 + j];
                const float* p = xf + (size_t)src * CH + c4 * 16;
                a0 += *(const floatx4*)p;
                a1 += *(const floatx4*)(p + 4);
                a2 += *(const floatx4*)(p + 8);
                a3 += *(const floatx4*)(p + 12);
            }
        }

        float inv = 1.0f / (float)max(d, 1);
        short8 mv0, mv1;
        #pragma unroll
        for (int i = 0; i < 4; i++) {
            mv0[i]     = (short)f2bf(a0[i] * inv);
            mv0[4 + i] = (short)f2bf(a1[i] * inv);
            mv1[i]     = (short)f2bf(a2[i] * inv);
            mv1[4 + i] = (short)f2bf(a3[i] * inv);
        }
        *(short8*)(&sm[wid][n16][c4 * 16])     = mv0;
        *(short8*)(&sm[wid][n16][c4 * 16 + 8]) = mv1;
    }

    // own-wave LDS ordering only — no block barrier
    asm volatile("s_waitcnt lgkmcnt(0)" ::: "memory");
    __builtin_amdgcn_sched_barrier(0);

    // ---------------- phase 2: full MFMA tile, this wave only --------------
    const int n_ = lane & 15;
    const int q_ = lane >> 4;

    short8 am0 = *(const short8*)(&sm[wid][n_][q_ * 8]);
    short8 am1 = *(const short8*)(&sm[wid][n_][32 + q_ * 8]);

    int node_m = tilebase + n_;
    int node_c = (node_m < n_nodes) ? node_m : 0;
    short8 ax0, ax1;
    if (xbf) {
        ax0 = *(const short8*)(xu + (size_t)node_c * CH + q_ * 8);
        ax1 = *(const short8*)(xu + (size_t)node_c * CH + 32 + q_ * 8);
    } else {
        const float* p = xf + (size_t)node_c * CH;
        #pragma unroll
        for (int j = 0; j < 8; j++) {
            ax0[j] = (short)f2bf(p[q_ * 8 + j]);
            ax1[j] = (short)f2bf(p[32 + q_ * 8 + j]);
        }
    }

    float p_acc[4] = {0, 0, 0, 0};
    unsigned short* ho = (unsigned short*)outp;

    #pragma unroll 1
    for (int t = 0; t < 4; t++) {
        int row = t * 16 + n_;           // out-channel
        short8 wlf0, wlf1, wrf0, wrf1;
        float bv, wov = 0.0f;
        if (isbf) {
            const unsigned short* wl = (const unsigned short*)w_l;
            const unsigned short* wr = (const unsigned short*)w_r;
            wlf0 = *(const short8*)(wl + row * CH + q_ * 8);
            wlf1 = *(const short8*)(wl + row * CH + 32 + q_ * 8);
            wrf0 = *(const short8*)(wr + row * CH + q_ * 8);
            wrf1 = *(const short8*)(wr + row * CH + 32 + q_ * 8);
            bv = bf2f(((const unsigned short*)bias)[row]);
            if (HEAD) wov = bf2f(((const unsigned short*)w_out)[row]);
        } else {
            const float* wl = (const float*)w_l;
            const float* wr = (const float*)w_r;
            #pragma unroll
            for (int j = 0; j < 8; j++) {
                wlf0[j] = (short)f2bf(wl[row * CH + q_ * 8 + j]);
                wlf1[j] = (short)f2bf(wl[row * CH + 32 + q_ * 8 + j]);
                wrf0[j] = (short)f2bf(wr[row * CH + q_ * 8 + j]);
                wrf1[j] = (short)f2bf(wr[row * CH + 32 + q_ * 8 + j]);
            }
            bv = ((const float*)bias)[row];
            if (HEAD) wov = ((const float*)w_out)[row];
        }

        floatx4 acc = {bv, bv, bv, bv};
        acc = __builtin_amdgcn_mfma_f32_16x16x32_bf16(am0, wlf0, acc, 0, 0, 0);
        acc = __builtin_amdgcn_mfma_f32_16x16x32_bf16(am1, wlf1, acc, 0, 0, 0);
        acc = __builtin_amdgcn_mfma_f32_16x16x32_bf16(ax0, wrf0, acc, 0, 0, 0);
        acc = __builtin_amdgcn_mfma_f32_16x16x32_bf16(ax1, wrf1, acc, 0, 0, 0);

        if (!HEAD) {
            int cc = t * 16 + n_;
            #pragma unroll
            for (int reg = 0; reg < 4; reg++) {
                int node_r = tilebase + q_ * 4 + reg;
                if (node_r < n_nodes)
                    ho[(size_t)node_r * CH + cc] = f2bf(fmaxf(acc[reg], 0.0f));
            }
        } else {
            #pragma unroll
            for (int reg = 0; reg < 4; reg++)
                p_acc[reg] += fmaxf(acc[reg], 0.0f) * wov;
        }
    }

    if (HEAD) {
        #pragma unroll
        for (int off = 1; off < 16; off <<= 1) {
            #pragma unroll
            for (int reg = 0; reg < 4; reg++)
                p_acc[reg] += __shfl_xor(p_acc[reg], off);
        }
        if (n_ == 0) {
            float bo = isbf ? bf2f(((const unsigned short*)b_out)[0])
                            : ((const float*)b_out)[0];
            #pragma unroll
            for (int reg = 0; reg < 4; reg++) {
                int node_r = tilebase + q_ * 4 + reg;
                if (node_r < n_nodes) {
                    float sg = 1.0f / (1.0f + expf(-(p_acc[reg] + bo)));
                    if (isbf) ((unsigned short*)outp)[node_r] = f2bf(sg);
                    else      ((float*)outp)[node_r] = sg;
                }
            }
        }
    }
}

extern "C" void kernel_launch(void* const* d_in, const int* in_sizes, int n_in,
                              void* d_out, int out_size, void* d_ws, size_t ws_size,
                              hipStream_t stream)
{
    const void* x    = d_in[0];
    const int*  ei   = (const int*)d_in[1];
    const void* w1_l = d_in[2];
    const void* b1   = d_in[3];
    const void* w1_r = d_in[4];
    const void* w2_l = d_in[5];
    const void* b2   = d_in[6];
    const void* w2_r = d_in[7];
    const void* wout = d_in[8];
    const void* bout = d_in[9];

    int n_nodes = out_size;
    int n_edges = in_sizes[1] / 2;
    const int* srcs = ei;
    const int* dsts = ei + n_edges;

    // ws: [flag][deg n][rowptr n+1][cursor n][bsum 1024][nbr E][h n*64]
    char* wsb = (char*)d_ws;
    size_t off = 0;
    auto carve = [&](size_t bytes) { size_t p = off; off = (off + bytes + 255) & ~(size_t)255; return p; };
    size_t flag_off = carve(sizeof(int));
    size_t deg_off  = carve((size_t)n_nodes * sizeof(int));
    size_t row_off  = carve((size_t)(n_nodes + 1) * sizeof(int));
    size_t cur_off  = carve((size_t)n_nodes * sizeof(int));
    size_t bs_off   = carve(1024 * sizeof(int));
    size_t nbr_off  = carve((size_t)n_edges * sizeof(int));
    size_t h_off    = carve((size_t)n_nodes * CH * sizeof(unsigned short));
    int* flag   = (int*)(wsb + flag_off);
    int* deg    = (int*)(wsb + deg_off);
    int* rowptr = (int*)(wsb + row_off);
    int* cursor = (int*)(wsb + cur_off);
    int* bsum   = (int*)(wsb + bs_off);
    int* nbr    = (int*)(wsb + nbr_off);
    unsigned short* h = (unsigned short*)(wsb + h_off);

    int eblocks = (n_edges + 255) / 256;
    int xblocks = 2048;                          // XCD-owned permute
    int nb1     = (n_nodes + 1023) / 1024;
    int fblocks = (n_nodes + 63) / 64;           // fused: 4 waves x 16-node tile

    hipMemsetAsync(deg, 0, (size_t)n_nodes * sizeof(int), stream);

    // CSR build (+ dtype detect inside k_hist)
    k_hist<<<eblocks, 256, 0, stream>>>((const unsigned short*)x, srcs, dsts, deg, flag, n_edges, n_nodes);
    k_scan1<<<nb1, 256, 0, stream>>>(deg, rowptr, bsum, n_nodes);
    k_scan2<<<1, 256, 0, stream>>>(bsum, rowptr, nb1, n_nodes);
    k_scan3<<<nb1, 256, 0, stream>>>(rowptr, cursor, bsum, n_nodes);
    k_permute<<<xblocks, 256, 0, stream>>>(srcs, dsts, cursor, nbr, n_edges, n_nodes);

    // layer 1: x -> h (wave-fused gather+mm)
    k_fused<0, false><<<fblocks, 256, 0, stream>>>(flag, x, nbr, rowptr,
                                                   w1_l, b1, w1_r,
                                                   nullptr, nullptr, h, n_nodes);
    // layer 2 + head: h -> out (wave-fused gather+mm+head)
    k_fused<1, true><<<fblocks, 256, 0, stream>>>(flag, h, nbr, rowptr,
                                                  w2_l, b2, w2_r,
                                                  wout, bout, d_out, n_nodes);
}